// Round 8
// baseline (152.326 us; speedup 1.0000x reference)
//
#include <hip/hip_runtime.h>
#include <hip/hip_bf16.h>
#include <math.h>

// Problem constants
#define TT  30
#define BNN 1024
#define HH  128
#define MT  (TT*BNN)     // 30720 rows
#define CAP 64           // max nnz per adjacency row (mean ~5.1, 64 is >25 sigma)

typedef short bf16x8 __attribute__((ext_vector_type(8)));
typedef float f32x4 __attribute__((ext_vector_type(4)));

// ---------- helpers ----------
__device__ __forceinline__ float ldf(const void* p, size_t i, int fp) {
  if (fp == 0) { // bf16
    unsigned int w = ((unsigned int)(((const unsigned short*)p)[i])) << 16;
    float f; __builtin_memcpy(&f, &w, 4); return f;
  }
  return ((const float*)p)[i];
}
__device__ __forceinline__ float bf2f(unsigned short u) {
  unsigned int w = ((unsigned int)u) << 16;
  float f; __builtin_memcpy(&f, &w, 4); return f;
}
__device__ __forceinline__ unsigned short f2bf(float f) { // RNE
  unsigned int u; __builtin_memcpy(&u, &f, 4);
  return (unsigned short)((u + 0x7FFFu + ((u >> 16) & 1u)) >> 16);
}
// split f32 into bf16 hi + bf16 lo (residual); hi+lo ~ a with ~2^-17 rel err
__device__ __forceinline__ void splitbf(float a, unsigned short& h, unsigned short& l) {
  h = f2bf(a);
  l = f2bf(a - bf2f(h));
}

// ---------- block-local deterministic dtype detection (same bytes every block -> same result) ----------
__device__ int block_detect_fp(const unsigned short* xw) {   // 0=bf16, 1=f32
  __shared__ int cnt_exp;
  if (threadIdx.x == 0) cnt_exp = 0;
  __syncthreads();
  int local = 0;
  for (int i = threadIdx.x; i < 2048; i += 256) {
    int e = (xw[i] >> 8) & 0x7F;
    if (e >= 0x3A && e <= 0x41) local++;
  }
  atomicAdd(&cnt_exp, local);
  __syncthreads();
  return (cnt_exp > 1536) ? 0 : 1;
}
__device__ int block_detect_ego(const unsigned int* ew) {    // 0=bf16,1=f32,2=bool8,3=int32
  __shared__ int f_odd1, f_any, f_nz;
  if (threadIdx.x == 0) { f_odd1 = 0; f_any = 0; f_nz = 0; }
  __syncthreads();
  int l1 = 0, l2 = 0, l3 = 0;
  for (int i = threadIdx.x; i < 7680; i += 256) {
    unsigned int w = ew[i];
    #pragma unroll
    for (int e = 0; e < 4; ++e) {
      unsigned char b = (w >> (8 * e)) & 0xff;
      if (b == 0x3F) { l2 = 1; if (e == 1) l1 = 1; }
      if (b != 0 && e != 0) l3 = 1;
    }
  }
  if (l1) atomicOr(&f_odd1, 1);
  if (l2) atomicOr(&f_any, 1);
  if (l3) atomicOr(&f_nz, 1);
  __syncthreads();
  return f_odd1 ? 0 : (f_any ? 1 : (f_nz ? 2 : 3));
}

// ---------- fused setup: detect + pe + weight prep + mask expand + combined QKV projections ----------
// bid 0: global mode write; [1,16): pe; [16,147): prep; [147,267): expand_mask; [267,462): combine3
__global__ __launch_bounds__(256) void setup_kernel(
    const void* x_raw, const void* ego,
    const void* W1, const void* b1, const void* W2, const void* b2, const void* Wo, const void* bo,
    const void* Wq, const void* bq, const void* Wk, const void* bk, const void* Wv, const void* bv,
    const void* Wqi, const void* bqi, const void* Wki, const void* bki, const void* Wvi, const void* bvi,
    int* mode, float* pe, float* W1f, float* b1f, float* b2f, float* bof,
    unsigned short* W2h, unsigned short* W2l, unsigned short* Woh, unsigned short* Wol,
    unsigned short* Wch, unsigned short* Wcl, float* bqkv, float* maskf) {
  int bid = blockIdx.x;
  if (bid == 0) {
    int fp = block_detect_fp((const unsigned short*)x_raw);
    int mm = block_detect_ego((const unsigned int*)ego);
    if (threadIdx.x == 0) { mode[0] = fp; mode[1] = mm; }
    return;
  }
  if (bid < 16) {
    // positional embedding (double precision, matches numpy)
    int idx = (bid - 1) * 256 + threadIdx.x;
    int t = idx >> 7, i = idx & 127, j = i >> 1;
    double div = exp((double)(2 * j) * (-log(10000.0) / 128.0));
    double ang = (double)t * div;
    pe[idx] = (i & 1) ? (float)cos(ang) : (float)sin(ang);
    return;
  }
  if (bid < 147) {
    int fp = block_detect_fp((const unsigned short*)x_raw);
    int idx = (bid - 16) * 256 + threadIdx.x;
    if (idx < 16384) { int k = idx >> 7, h = idx & 127; splitbf(ldf(W2, idx, fp), W2h[h * 128 + k], W2l[h * 128 + k]); return; }
    idx -= 16384;
    if (idx < 16384) { int k = idx >> 7, h = idx & 127; splitbf(ldf(Wo, idx, fp), Woh[h * 128 + k], Wol[h * 128 + k]); return; }
    idx -= 16384;
    if (idx < 384) { W1f[idx] = ldf(W1, idx, fp); return; } idx -= 384;
    if (idx < 128) { b1f[idx] = ldf(b1, idx, fp); return; } idx -= 128;
    if (idx < 128) { b2f[idx] = ldf(b2, idx, fp); return; } idx -= 128;
    if (idx < 128) { bof[idx] = ldf(bo, idx, fp); return; }
    return;
  }
  if (bid < 267) {
    // ego mask (B,T,N) -> (T,BN) as f32 0/1
    int mm = block_detect_ego((const unsigned int*)ego);
    int idx = (bid - 147) * 256 + threadIdx.x;
    int t = idx >> 10, p = idx & 1023, b = p >> 8, n = p & 255;
    size_t e = (size_t)b * (TT * 256) + (size_t)t * 256 + n;
    bool nz;
    if      (mm == 0) nz = ((const unsigned short*)ego)[e] != 0;
    else if (mm == 1) nz = ((const float*)ego)[e] != 0.f;
    else if (mm == 2) nz = ((const unsigned char*)ego)[e] != 0;
    else              nz = ((const int*)ego)[e] != 0;
    maskf[idx] = nz ? 1.f : 0.f;
    return;
  }
  // combine3: (Wa@Wb)^T split hi/lo bf16; bc = ba@Wb + bb (f32)
  int fp = block_detect_fp((const unsigned short*)x_raw);
  int cb = bid - 267;
  int g = cb / 65;
  const void* Wa = (g == 0) ? Wq : (g == 1) ? Wk : Wv;
  const void* ba = (g == 0) ? bq : (g == 1) ? bk : bv;
  const void* Wb = (g == 0) ? Wqi : (g == 1) ? Wki : Wvi;
  const void* bb = (g == 0) ? bqi : (g == 1) ? bki : bvi;
  unsigned short* Wh = Wch + (size_t)g * 16384;
  unsigned short* Wl = Wcl + (size_t)g * 16384;
  float* bc = bqkv + g * 128;
  int idx = (cb % 65) * 256 + threadIdx.x;
  if (idx < 16384) {
    int k = idx >> 7, h = idx & 127;
    float s = 0.f;
    #pragma unroll 8
    for (int m = 0; m < 128; ++m) s += ldf(Wa, k * 128 + m, fp) * ldf(Wb, m * 128 + h, fp);
    splitbf(s, Wh[h * 128 + k], Wl[h * 128 + k]);
  } else if (idx < 16512) {
    int h = idx - 16384;
    float s = ldf(bb, h, fp);
    #pragma unroll 8
    for (int m = 0; m < 128; ++m) s += ldf(ba, m, fp) * ldf(Wb, m * 128 + h, fp);
    bc[h] = s;
  }
}

// ---------- CSR build + degree/dinv (deterministic, ballot-ordered, vectorized loads) ----------
__global__ __launch_bounds__(256) void csr_kernel(const void* A, const int* mode, const float* maskf,
                                                  int* nnz, int* cols, float* dinv) {
  int fp = mode[0];
  int r = blockIdx.x * 4 + (threadIdx.x >> 6);
  int lane = threadIdx.x & 63;
  int t = r >> 10, i = r & 1023;
  int tb = t << 10;
  if (maskf[r] == 0.f) { if (lane == 0) { nnz[r] = 0; dinv[r] = 0.f; } return; }
  int* myc = cols + (size_t)r * CAP;
  int cnt = 0;
  unsigned long long lmask = (1ull << lane) - 1ull;
  if (fp == 1) {
    const float* Ar = (const float*)A + (size_t)t * BNN * BNN + (size_t)i * BNN;
    #pragma unroll
    for (int it = 0; it < 4; ++it) {
      int j0 = it * 256 + lane * 4;
      float4 av = *(const float4*)(Ar + j0);
      float4 mv = *(const float4*)(maskf + tb + j0);
      float va[4] = {av.x * mv.x, av.y * mv.y, av.z * mv.z, av.w * mv.w};
      #pragma unroll
      for (int e = 0; e < 4; ++e) {
        bool hit = va[e] != 0.f;
        unsigned long long bal = __ballot(hit);
        if (hit) { int pos = cnt + __popcll(bal & lmask); if (pos < CAP) myc[pos] = j0 + e; }
        cnt += __popcll(bal);
      }
    }
  } else {
    const unsigned short* Ar = (const unsigned short*)A + (size_t)t * BNN * BNN + (size_t)i * BNN;
    #pragma unroll
    for (int it = 0; it < 2; ++it) {
      int j0 = it * 512 + lane * 8;
      uint4 av = *(const uint4*)(Ar + j0);
      unsigned int wv[4] = {av.x, av.y, av.z, av.w};
      float4 m0 = *(const float4*)(maskf + tb + j0);
      float4 m1 = *(const float4*)(maskf + tb + j0 + 4);
      float mm[8] = {m0.x, m0.y, m0.z, m0.w, m1.x, m1.y, m1.z, m1.w};
      #pragma unroll
      for (int e = 0; e < 8; ++e) {
        unsigned short u = (wv[e >> 1] >> ((e & 1) * 16)) & 0xffff;
        bool hit = (u != 0) && (mm[e] != 0.f);
        unsigned long long bal = __ballot(hit);
        if (hit) { int pos = cnt + __popcll(bal & lmask); if (pos < CAP) myc[pos] = j0 + e; }
        cnt += __popcll(bal);
      }
    }
  }
  if (lane == 0) { nnz[r] = cnt > CAP ? CAP : cnt; dinv[r] = rsqrtf((float)cnt + 1.0f); }
}

// ---------- GCN layer 1: h1 = relu(dinv_r*(S @ W1) + b1), S = sum_j dinv_j x_j; writes hi/lo bf16 ----------
__global__ __launch_bounds__(256) void spmm1_kernel(const void* x, const int* mode, const int* nnz,
    const int* cols, const float* dinv, const float* W1f, const float* b1f,
    unsigned short* h1h, unsigned short* h1l) {
  int fp = mode[0];
  int r = blockIdx.x * 4 + (threadIdx.x >> 6);
  int lane = threadIdx.x & 63;
  int tbase = (r >> 10) << 10;  // t * 1024
  int n = nnz[r];
  float s0 = 0.f, s1 = 0.f, s2 = 0.f;
  int j = -1;
  if (lane < n) j = tbase + cols[(size_t)r * CAP + lane];   // GLOBAL row id
  else if (lane == n) j = r;  // self-loop term; n<64 guaranteed
  if (j >= 0) {
    float dj = dinv[j];
    s0 = dj * ldf(x, (size_t)j * 3 + 0, fp);
    s1 = dj * ldf(x, (size_t)j * 3 + 1, fp);
    s2 = dj * ldf(x, (size_t)j * 3 + 2, fp);
  }
  #pragma unroll
  for (int d = 1; d < 64; d <<= 1) {
    s0 += __shfl_xor(s0, d);
    s1 += __shfl_xor(s1, d);
    s2 += __shfl_xor(s2, d);
  }
  float dr = dinv[r];
  #pragma unroll
  for (int u = 0; u < 2; ++u) {
    int h = lane + u * 64;
    float v = dr * (s0 * W1f[h] + s1 * W1f[128 + h] + s2 * W1f[256 + h]) + b1f[h];
    splitbf(fmaxf(v, 0.f), h1h[(size_t)r * 128 + h], h1l[(size_t)r * 128 + h]);
  }
}

// ---------- GCN layer 2 sparse aggregate + epilogue -> x_seq hi/lo bf16 (wave per row, float2/lane) ----------
__global__ __launch_bounds__(256) void spmm2_kernel(const float* g2s, const int* nnz, const int* cols,
    const float* dinv, const float* b2f, const float* maskf, const float* pe,
    unsigned short* xh, unsigned short* xl) {
  int r = blockIdx.x * 4 + (threadIdx.x >> 6);
  int lane = threadIdx.x & 63;
  int c = lane * 2;
  int t = r >> 10, i = r & 1023;
  int n = nnz[r];
  const int* myc = cols + (size_t)r * CAP;
  const float* st = g2s + ((size_t)(t << 10)) * 128;
  float2 acc = *(const float2*)(g2s + (size_t)r * 128 + c);   // self term
  for (int s = 0; s < n; ++s) {
    float2 v = *(const float2*)(st + (size_t)myc[s] * 128 + c);
    acc.x += v.x; acc.y += v.y;
  }
  float dr = dinv[r], m = maskf[r];
  float2 b = *(const float2*)(b2f + c);
  float2 p = *(const float2*)(pe + t * 128 + c);
  float vx = fmaxf(dr * acc.x + b.x, 0.f) * m + p.x;
  float vy = fmaxf(dr * acc.y + b.y, 0.f) * m + p.y;
  size_t o = ((size_t)i * TT + t) * 128 + c;
  splitbf(vx, xh[o], xl[o]);
  splitbf(vy, xh[o + 1], xl[o + 1]);
}

// ---------- split-precision MFMA GEMM v3: pre-split A hi/lo, 64-row tiles, 48 KB LDS, internal g-loop ----------
// (M x 128) @ (128 x 128) x ng; B pre-split hi/lo [n][k]. acc = Ah*Bl + Al*Bh + Ah*Bh (bit-identical to v2).
__global__ __launch_bounds__(256) void mfma_gemm(const unsigned short* Ahi, const unsigned short* Alo,
    const unsigned short* Bhi, const unsigned short* Blo, int ng,
    const float* scale, const float* bias, float* outf, void* outfin, const int* mode) {
  __shared__ __align__(16) unsigned short Ah[64 * 64];    // 8 KB
  __shared__ __align__(16) unsigned short Al[64 * 64];    // 8 KB
  __shared__ __align__(16) unsigned short Bh[128 * 64];   // 16 KB
  __shared__ __align__(16) unsigned short Bl[128 * 64];   // 16 KB
  int tid = threadIdx.x;
  int rowTile = blockIdx.x * 64;
  int lane = tid & 63;
  int wid = tid >> 6;
  int wrow = (wid >> 1) * 32, wcol = (wid & 1) * 64;
  int fp = mode[0];

  for (int g = 0; g < ng; ++g) {
    const unsigned short* Bhp = Bhi + (size_t)g * 16384;
    const unsigned short* Blp = Blo + (size_t)g * 16384;
    f32x4 acc[2][4];
    #pragma unroll
    for (int m = 0; m < 2; ++m)
      #pragma unroll
      for (int n = 0; n < 4; ++n) acc[m][n] = (f32x4){0.f, 0.f, 0.f, 0.f};

    for (int kb = 0; kb < 2; ++kb) {
      __syncthreads();
      // stage A (pure copy of pre-split rows)
      #pragma unroll
      for (int it = 0; it < 2; ++it) {
        int c = it * 256 + tid;
        int r = c >> 3, cc = c & 7;
        int swz = (cc ^ (r & 7)) * 16;
        size_t src = (size_t)(rowTile + r) * 128 + kb * 64 + cc * 8;
        *(uint4*)((char*)Ah + r * 128 + swz) = *(const uint4*)(Ahi + src);
        *(uint4*)((char*)Al + r * 128 + swz) = *(const uint4*)(Alo + src);
      }
      // stage B
      #pragma unroll
      for (int it = 0; it < 4; ++it) {
        int c = it * 256 + tid;
        int r = c >> 3, cc = c & 7;
        int swz = (cc ^ (r & 7)) * 16;
        *(uint4*)((char*)Bh + r * 128 + swz) = *(const uint4*)(Bhp + (size_t)r * 128 + kb * 64 + cc * 8);
        *(uint4*)((char*)Bl + r * 128 + swz) = *(const uint4*)(Blp + (size_t)r * 128 + kb * 64 + cc * 8);
      }
      __syncthreads();
      #pragma unroll
      for (int ks = 0; ks < 2; ++ks) {
        bf16x8 ah[2], al[2], bh[4], bl[4];
        #pragma unroll
        for (int m = 0; m < 2; ++m) {
          int R = wrow + m * 16 + (lane & 15);
          int cc = ks * 4 + (lane >> 4);
          int off = R * 128 + ((cc ^ (R & 7)) * 16);
          ah[m] = *(const bf16x8*)((const char*)Ah + off);
          al[m] = *(const bf16x8*)((const char*)Al + off);
        }
        #pragma unroll
        for (int n = 0; n < 4; ++n) {
          int R = wcol + n * 16 + (lane & 15);
          int cc = ks * 4 + (lane >> 4);
          int off = R * 128 + ((cc ^ (R & 7)) * 16);
          bh[n] = *(const bf16x8*)((const char*)Bh + off);
          bl[n] = *(const bf16x8*)((const char*)Bl + off);
        }
        #pragma unroll
        for (int m = 0; m < 2; ++m)
          #pragma unroll
          for (int n = 0; n < 4; ++n) {
            acc[m][n] = __builtin_amdgcn_mfma_f32_16x16x32_bf16(ah[m], bl[n], acc[m][n], 0, 0, 0);
            acc[m][n] = __builtin_amdgcn_mfma_f32_16x16x32_bf16(al[m], bh[n], acc[m][n], 0, 0, 0);
            acc[m][n] = __builtin_amdgcn_mfma_f32_16x16x32_bf16(ah[m], bh[n], acc[m][n], 0, 0, 0);
          }
      }
    }
    const float* bp = bias ? (bias + g * 128) : nullptr;
    float* ofp = outf ? (outf + (size_t)g * ((size_t)MT * 128)) : nullptr;
    #pragma unroll
    for (int m = 0; m < 2; ++m) {
      #pragma unroll
      for (int n = 0; n < 4; ++n) {
        int col = wcol + n * 16 + (lane & 15);
        float bv = bp ? bp[col] : 0.f;
        #pragma unroll
        for (int q = 0; q < 4; ++q) {
          int row = rowTile + wrow + m * 16 + (lane >> 4) * 4 + q;
          float v = acc[m][n][q];
          if (scale) v *= scale[row];
          v += bv;
          size_t o = (size_t)row * 128 + col;
          if (ofp)           ofp[o] = v;
          else if (fp == 0)  ((unsigned short*)outfin)[o] = f2bf(v);
          else               ((float*)outfin)[o] = v;
        }
      }
    }
  }
}

// ---------- attention: thread=(head,t); q,scores,probs in registers; writes o split hi/lo ----------
__global__ __launch_bounds__(256) void attn_kernel(const float* Q, const float* K, const float* V,
                                                   unsigned short* obh, unsigned short* obl) {
  __shared__ __align__(16) float ksm[TT * 128];
  __shared__ __align__(16) float vsm[TT * 128];
  int tid = threadIdx.x;
  size_t base = (size_t)blockIdx.x * (TT * 128);
  for (int i = tid; i < TT * 128 / 4; i += 256) {
    ((float4*)ksm)[i] = ((const float4*)(K + base))[i];
    ((float4*)vsm)[i] = ((const float4*)(V + base))[i];
  }
  int h = tid >> 5, t = tid & 31;
  float q[16];
  if (t < TT) {
    const float4* qp = (const float4*)(Q + base + (size_t)t * 128 + h * 16);
    #pragma unroll
    for (int e = 0; e < 4; ++e) { float4 f = qp[e]; q[4*e] = f.x; q[4*e+1] = f.y; q[4*e+2] = f.z; q[4*e+3] = f.w; }
  }
  __syncthreads();
  if (t >= TT) return;
  float p[TT];
  float mx = -1e30f;
  #pragma unroll
  for (int s = 0; s < TT; ++s) {
    const float4* kp = (const float4*)&ksm[s * 128 + h * 16];
    float d = 0.f;
    #pragma unroll
    for (int e = 0; e < 4; ++e) {
      float4 f = kp[e];
      d += q[4*e] * f.x + q[4*e+1] * f.y + q[4*e+2] * f.z + q[4*e+3] * f.w;
    }
    p[s] = d * 0.25f;  // 1/sqrt(16)
    mx = fmaxf(mx, p[s]);
  }
  float sum = 0.f;
  #pragma unroll
  for (int s = 0; s < TT; ++s) { p[s] = __expf(p[s] - mx); sum += p[s]; }
  float inv = 1.f / sum;
  float o[16];
  #pragma unroll
  for (int e = 0; e < 16; ++e) o[e] = 0.f;
  #pragma unroll
  for (int s = 0; s < TT; ++s) {
    const float4* vp = (const float4*)&vsm[s * 128 + h * 16];
    float ps = p[s] * inv;
    #pragma unroll
    for (int e = 0; e < 4; ++e) {
      float4 f = vp[e];
      o[4*e] += ps * f.x; o[4*e+1] += ps * f.y; o[4*e+2] += ps * f.z; o[4*e+3] += ps * f.w;
    }
  }
  unsigned short hi[16], lo[16];
  #pragma unroll
  for (int e = 0; e < 16; ++e) splitbf(o[e], hi[e], lo[e]);
  size_t oo = base + (size_t)t * 128 + h * 16;
  uint4 ph0, ph1, pl0, pl1;
  ph0.x = hi[0] | ((unsigned)hi[1] << 16);  ph0.y = hi[2] | ((unsigned)hi[3] << 16);
  ph0.z = hi[4] | ((unsigned)hi[5] << 16);  ph0.w = hi[6] | ((unsigned)hi[7] << 16);
  ph1.x = hi[8] | ((unsigned)hi[9] << 16);  ph1.y = hi[10] | ((unsigned)hi[11] << 16);
  ph1.z = hi[12] | ((unsigned)hi[13] << 16); ph1.w = hi[14] | ((unsigned)hi[15] << 16);
  pl0.x = lo[0] | ((unsigned)lo[1] << 16);  pl0.y = lo[2] | ((unsigned)lo[3] << 16);
  pl0.z = lo[4] | ((unsigned)lo[5] << 16);  pl0.w = lo[6] | ((unsigned)lo[7] << 16);
  pl1.x = lo[8] | ((unsigned)lo[9] << 16);  pl1.y = lo[10] | ((unsigned)lo[11] << 16);
  pl1.z = lo[12] | ((unsigned)lo[13] << 16); pl1.w = lo[14] | ((unsigned)lo[15] << 16);
  *(uint4*)(obh + oo) = ph0; *(uint4*)(obh + oo + 8) = ph1;
  *(uint4*)(obl + oo) = pl0; *(uint4*)(obl + oo + 8) = pl1;
}

// ---------- launch ----------
extern "C" void kernel_launch(void* const* d_in, const int* in_sizes, int n_in,
                              void* d_out, int out_size, void* d_ws, size_t ws_size,
                              hipStream_t stream) {
  (void)in_sizes; (void)n_in; (void)out_size;
  const void* x_raw = d_in[0];
  const void* adj   = d_in[1];
  const void* ego   = d_in[2];
  const void* W1 = d_in[3];  const void* b1 = d_in[4];
  const void* W2 = d_in[5];  const void* b2 = d_in[6];
  const void* Wq = d_in[7];  const void* bq = d_in[8];
  const void* Wk = d_in[9];  const void* bk = d_in[10];
  const void* Wv = d_in[11]; const void* bv = d_in[12];
  const void* Wqi = d_in[13]; const void* bqi = d_in[14];
  const void* Wki = d_in[15]; const void* bki = d_in[16];
  const void* Wvi = d_in[17]; const void* bvi = d_in[18];
  const void* Wo = d_in[19]; const void* bo = d_in[20];

  char* w = (char*)d_ws;
  auto alloc = [&](size_t b) { char* p = w; w += (b + 255) & ~(size_t)255; return p; };
  int*   mode  = (int*)  alloc(16);
  float* maskf = (float*)alloc((size_t)MT * 4);
  float* dinv  = (float*)alloc((size_t)MT * 4);
  float* pe    = (float*)alloc((size_t)TT * HH * 4);
  float* W1f   = (float*)alloc(384 * 4);
  float* b1f   = (float*)alloc(128 * 4);
  float* b2f   = (float*)alloc(128 * 4);
  float* bof   = (float*)alloc(128 * 4);
  unsigned short* W2h = (unsigned short*)alloc(16384 * 2);
  unsigned short* W2l = (unsigned short*)alloc(16384 * 2);
  unsigned short* Woh = (unsigned short*)alloc(16384 * 2);
  unsigned short* Wol = (unsigned short*)alloc(16384 * 2);
  unsigned short* Wch = (unsigned short*)alloc((size_t)3 * 16384 * 2);
  unsigned short* Wcl = (unsigned short*)alloc((size_t)3 * 16384 * 2);
  float* bqkv  = (float*)alloc(3 * 128 * 4);
  int*   nnz   = (int*)  alloc((size_t)MT * 4);
  int*   cols  = (int*)  alloc((size_t)MT * CAP * 4);
  unsigned short* h1h = (unsigned short*)alloc((size_t)MT * 128 * 2);
  unsigned short* h1l = (unsigned short*)alloc((size_t)MT * 128 * 2);
  unsigned short* xh  = (unsigned short*)alloc((size_t)MT * 128 * 2);
  unsigned short* xl  = (unsigned short*)alloc((size_t)MT * 128 * 2);
  unsigned short* obh = (unsigned short*)alloc((size_t)MT * 128 * 2);
  unsigned short* obl = (unsigned short*)alloc((size_t)MT * 128 * 2);
  float* g2s   = (float*)alloc((size_t)MT * 128 * 4);
  float* qkv   = (float*)alloc((size_t)3 * MT * 128 * 4);
  size_t need = (size_t)(w - (char*)d_ws);
  if (need > ws_size) return;  // diagnostic: absmax will equal max|ref|

  setup_kernel<<<462, 256, 0, stream>>>(x_raw, ego, W1, b1, W2, b2, Wo, bo,
                                        Wq, bq, Wk, bk, Wv, bv, Wqi, bqi, Wki, bki, Wvi, bvi,
                                        mode, pe, W1f, b1f, b2f, bof,
                                        W2h, W2l, Woh, Wol, Wch, Wcl, bqkv, maskf);
  csr_kernel<<<MT / 4, 256, 0, stream>>>(adj, mode, maskf, nnz, cols, dinv);
  spmm1_kernel<<<MT / 4, 256, 0, stream>>>(x_raw, mode, nnz, cols, dinv, W1f, b1f, h1h, h1l);
  mfma_gemm<<<480, 256, 0, stream>>>(h1h, h1l, W2h, W2l, 1, dinv, nullptr, g2s, nullptr, mode);
  spmm2_kernel<<<MT / 4, 256, 0, stream>>>(g2s, nnz, cols, dinv, b2f, maskf, pe, xh, xl);
  mfma_gemm<<<480, 256, 0, stream>>>(xh, xl, Wch, Wcl, 3, nullptr, bqkv, qkv, nullptr, mode);
  attn_kernel<<<BNN, 256, 0, stream>>>(qkv, qkv + (size_t)MT * 128, qkv + (size_t)2 * MT * 128, obh, obl);
  mfma_gemm<<<480, 256, 0, stream>>>(obh, obl, Woh, Wol, 1, nullptr, bof, nullptr, d_out, mode);
}

// Round 9
// 128.423 us; speedup vs baseline: 1.1861x; 1.1861x over previous
//
#include <hip/hip_runtime.h>
#include <hip/hip_bf16.h>
#include <math.h>

// Problem constants
#define TT  30
#define BNN 1024
#define HH  128
#define MT  (TT*BNN)     // 30720 rows
#define CAP 64           // max nnz per adjacency row (mean ~5.1, 64 is >25 sigma)

typedef short bf16x8 __attribute__((ext_vector_type(8)));
typedef float f32x4 __attribute__((ext_vector_type(4)));

// ---------- helpers ----------
__device__ __forceinline__ float ldf(const void* p, size_t i, int fp) {
  if (fp == 0) { // bf16
    unsigned int w = ((unsigned int)(((const unsigned short*)p)[i])) << 16;
    float f; __builtin_memcpy(&f, &w, 4); return f;
  }
  return ((const float*)p)[i];
}
__device__ __forceinline__ float bf2f(unsigned short u) {
  unsigned int w = ((unsigned int)u) << 16;
  float f; __builtin_memcpy(&f, &w, 4); return f;
}
__device__ __forceinline__ unsigned short f2bf(float f) { // RNE
  unsigned int u; __builtin_memcpy(&u, &f, 4);
  return (unsigned short)((u + 0x7FFFu + ((u >> 16) & 1u)) >> 16);
}
// split f32 into bf16 hi + bf16 lo (residual); hi+lo ~ a with ~2^-17 rel err
__device__ __forceinline__ void splitbf(float a, unsigned short& h, unsigned short& l) {
  h = f2bf(a);
  l = f2bf(a - bf2f(h));
}

// ---------- block-local deterministic dtype detection (same bytes every block -> same result) ----------
__device__ int block_detect_fp(const unsigned short* xw) {   // 0=bf16, 1=f32
  __shared__ int cnt_exp;
  if (threadIdx.x == 0) cnt_exp = 0;
  __syncthreads();
  int local = 0;
  for (int i = threadIdx.x; i < 2048; i += 256) {
    int e = (xw[i] >> 8) & 0x7F;
    if (e >= 0x3A && e <= 0x41) local++;
  }
  atomicAdd(&cnt_exp, local);
  __syncthreads();
  return (cnt_exp > 1536) ? 0 : 1;
}
__device__ int block_detect_ego(const unsigned int* ew) {    // 0=bf16,1=f32,2=bool8,3=int32
  __shared__ int f_odd1, f_any, f_nz;
  if (threadIdx.x == 0) { f_odd1 = 0; f_any = 0; f_nz = 0; }
  __syncthreads();
  int l1 = 0, l2 = 0, l3 = 0;
  for (int i = threadIdx.x; i < 7680; i += 256) {
    unsigned int w = ew[i];
    #pragma unroll
    for (int e = 0; e < 4; ++e) {
      unsigned char b = (w >> (8 * e)) & 0xff;
      if (b == 0x3F) { l2 = 1; if (e == 1) l1 = 1; }
      if (b != 0 && e != 0) l3 = 1;
    }
  }
  if (l1) atomicOr(&f_odd1, 1);
  if (l2) atomicOr(&f_any, 1);
  if (l3) atomicOr(&f_nz, 1);
  __syncthreads();
  return f_odd1 ? 0 : (f_any ? 1 : (f_nz ? 2 : 3));
}

// ---------- fused setup: detect + pe + weight prep + mask expand + combined QKV projections ----------
// bid 0: global mode write; [1,16): pe; [16,147): prep; [147,267): expand_mask; [267,462): combine3
__global__ __launch_bounds__(256) void setup_kernel(
    const void* x_raw, const void* ego,
    const void* W1, const void* b1, const void* W2, const void* b2, const void* Wo, const void* bo,
    const void* Wq, const void* bq, const void* Wk, const void* bk, const void* Wv, const void* bv,
    const void* Wqi, const void* bqi, const void* Wki, const void* bki, const void* Wvi, const void* bvi,
    int* mode, float* pe, float* W1f, float* b1f, float* b2f, float* bof,
    unsigned short* W2h, unsigned short* W2l, unsigned short* Woh, unsigned short* Wol,
    unsigned short* Wch, unsigned short* Wcl, float* bqkv, float* maskf) {
  int bid = blockIdx.x;
  if (bid == 0) {
    int fp = block_detect_fp((const unsigned short*)x_raw);
    int mm = block_detect_ego((const unsigned int*)ego);
    if (threadIdx.x == 0) { mode[0] = fp; mode[1] = mm; }
    return;
  }
  if (bid < 16) {
    // positional embedding (double precision, matches numpy)
    int idx = (bid - 1) * 256 + threadIdx.x;
    int t = idx >> 7, i = idx & 127, j = i >> 1;
    double div = exp((double)(2 * j) * (-log(10000.0) / 128.0));
    double ang = (double)t * div;
    pe[idx] = (i & 1) ? (float)cos(ang) : (float)sin(ang);
    return;
  }
  if (bid < 147) {
    int fp = block_detect_fp((const unsigned short*)x_raw);
    int idx = (bid - 16) * 256 + threadIdx.x;
    if (idx < 16384) { int k = idx >> 7, h = idx & 127; splitbf(ldf(W2, idx, fp), W2h[h * 128 + k], W2l[h * 128 + k]); return; }
    idx -= 16384;
    if (idx < 16384) { int k = idx >> 7, h = idx & 127; splitbf(ldf(Wo, idx, fp), Woh[h * 128 + k], Wol[h * 128 + k]); return; }
    idx -= 16384;
    if (idx < 384) { W1f[idx] = ldf(W1, idx, fp); return; } idx -= 384;
    if (idx < 128) { b1f[idx] = ldf(b1, idx, fp); return; } idx -= 128;
    if (idx < 128) { b2f[idx] = ldf(b2, idx, fp); return; } idx -= 128;
    if (idx < 128) { bof[idx] = ldf(bo, idx, fp); return; }
    return;
  }
  if (bid < 267) {
    // ego mask (B,T,N) -> (T,BN) as f32 0/1
    int mm = block_detect_ego((const unsigned int*)ego);
    int idx = (bid - 147) * 256 + threadIdx.x;
    int t = idx >> 10, p = idx & 1023, b = p >> 8, n = p & 255;
    size_t e = (size_t)b * (TT * 256) + (size_t)t * 256 + n;
    bool nz;
    if      (mm == 0) nz = ((const unsigned short*)ego)[e] != 0;
    else if (mm == 1) nz = ((const float*)ego)[e] != 0.f;
    else if (mm == 2) nz = ((const unsigned char*)ego)[e] != 0;
    else              nz = ((const int*)ego)[e] != 0;
    maskf[idx] = nz ? 1.f : 0.f;
    return;
  }
  // combine3: (Wa@Wb)^T split hi/lo bf16; bc = ba@Wb + bb (f32)
  int fp = block_detect_fp((const unsigned short*)x_raw);
  int cb = bid - 267;
  int g = cb / 65;
  const void* Wa = (g == 0) ? Wq : (g == 1) ? Wk : Wv;
  const void* ba = (g == 0) ? bq : (g == 1) ? bk : bv;
  const void* Wb = (g == 0) ? Wqi : (g == 1) ? Wki : Wvi;
  const void* bb = (g == 0) ? bqi : (g == 1) ? bki : bvi;
  unsigned short* Wh = Wch + (size_t)g * 16384;
  unsigned short* Wl = Wcl + (size_t)g * 16384;
  float* bc = bqkv + g * 128;
  int idx = (cb % 65) * 256 + threadIdx.x;
  if (idx < 16384) {
    int k = idx >> 7, h = idx & 127;
    float s = 0.f;
    #pragma unroll 8
    for (int m = 0; m < 128; ++m) s += ldf(Wa, k * 128 + m, fp) * ldf(Wb, m * 128 + h, fp);
    splitbf(s, Wh[h * 128 + k], Wl[h * 128 + k]);
  } else if (idx < 16512) {
    int h = idx - 16384;
    float s = ldf(bb, h, fp);
    #pragma unroll 8
    for (int m = 0; m < 128; ++m) s += ldf(ba, m, fp) * ldf(Wb, m * 128 + h, fp);
    bc[h] = s;
  }
}

// ---------- CSR build + degree/dinv (deterministic, ballot-ordered, vectorized loads) ----------
__global__ __launch_bounds__(256) void csr_kernel(const void* A, const int* mode, const float* maskf,
                                                  int* nnz, int* cols, float* dinv) {
  int fp = mode[0];
  int r = blockIdx.x * 4 + (threadIdx.x >> 6);
  int lane = threadIdx.x & 63;
  int t = r >> 10, i = r & 1023;
  int tb = t << 10;
  if (maskf[r] == 0.f) { if (lane == 0) { nnz[r] = 0; dinv[r] = 0.f; } return; }
  int* myc = cols + (size_t)r * CAP;
  int cnt = 0;
  unsigned long long lmask = (1ull << lane) - 1ull;
  if (fp == 1) {
    const float* Ar = (const float*)A + (size_t)t * BNN * BNN + (size_t)i * BNN;
    #pragma unroll
    for (int it = 0; it < 4; ++it) {
      int j0 = it * 256 + lane * 4;
      float4 av = *(const float4*)(Ar + j0);
      float4 mv = *(const float4*)(maskf + tb + j0);
      float va[4] = {av.x * mv.x, av.y * mv.y, av.z * mv.z, av.w * mv.w};
      #pragma unroll
      for (int e = 0; e < 4; ++e) {
        bool hit = va[e] != 0.f;
        unsigned long long bal = __ballot(hit);
        if (hit) { int pos = cnt + __popcll(bal & lmask); if (pos < CAP) myc[pos] = j0 + e; }
        cnt += __popcll(bal);
      }
    }
  } else {
    const unsigned short* Ar = (const unsigned short*)A + (size_t)t * BNN * BNN + (size_t)i * BNN;
    #pragma unroll
    for (int it = 0; it < 2; ++it) {
      int j0 = it * 512 + lane * 8;
      uint4 av = *(const uint4*)(Ar + j0);
      unsigned int wv[4] = {av.x, av.y, av.z, av.w};
      float4 m0 = *(const float4*)(maskf + tb + j0);
      float4 m1 = *(const float4*)(maskf + tb + j0 + 4);
      float mm[8] = {m0.x, m0.y, m0.z, m0.w, m1.x, m1.y, m1.z, m1.w};
      #pragma unroll
      for (int e = 0; e < 8; ++e) {
        unsigned short u = (wv[e >> 1] >> ((e & 1) * 16)) & 0xffff;
        bool hit = (u != 0) && (mm[e] != 0.f);
        unsigned long long bal = __ballot(hit);
        if (hit) { int pos = cnt + __popcll(bal & lmask); if (pos < CAP) myc[pos] = j0 + e; }
        cnt += __popcll(bal);
      }
    }
  }
  if (lane == 0) { nnz[r] = cnt > CAP ? CAP : cnt; dinv[r] = rsqrtf((float)cnt + 1.0f); }
}

// ---------- GCN layer 1: h1 = relu(dinv_r*(S @ W1) + b1), S = sum_j dinv_j x_j; writes hi/lo bf16 ----------
__global__ __launch_bounds__(256) void spmm1_kernel(const void* x, const int* mode, const int* nnz,
    const int* cols, const float* dinv, const float* W1f, const float* b1f,
    unsigned short* h1h, unsigned short* h1l) {
  int fp = mode[0];
  int r = blockIdx.x * 4 + (threadIdx.x >> 6);
  int lane = threadIdx.x & 63;
  int tbase = (r >> 10) << 10;  // t * 1024
  int n = nnz[r];
  float s0 = 0.f, s1 = 0.f, s2 = 0.f;
  int j = -1;
  if (lane < n) j = tbase + cols[(size_t)r * CAP + lane];   // GLOBAL row id
  else if (lane == n) j = r;  // self-loop term; n<64 guaranteed
  if (j >= 0) {
    float dj = dinv[j];
    s0 = dj * ldf(x, (size_t)j * 3 + 0, fp);
    s1 = dj * ldf(x, (size_t)j * 3 + 1, fp);
    s2 = dj * ldf(x, (size_t)j * 3 + 2, fp);
  }
  #pragma unroll
  for (int d = 1; d < 64; d <<= 1) {
    s0 += __shfl_xor(s0, d);
    s1 += __shfl_xor(s1, d);
    s2 += __shfl_xor(s2, d);
  }
  float dr = dinv[r];
  #pragma unroll
  for (int u = 0; u < 2; ++u) {
    int h = lane + u * 64;
    float v = dr * (s0 * W1f[h] + s1 * W1f[128 + h] + s2 * W1f[256 + h]) + b1f[h];
    splitbf(fmaxf(v, 0.f), h1h[(size_t)r * 128 + h], h1l[(size_t)r * 128 + h]);
  }
}

// ---------- GCN layer 2 sparse aggregate + epilogue -> x_seq hi/lo bf16 (wave per row, float2/lane) ----------
__global__ __launch_bounds__(256) void spmm2_kernel(const float* g2s, const int* nnz, const int* cols,
    const float* dinv, const float* b2f, const float* maskf, const float* pe,
    unsigned short* xh, unsigned short* xl) {
  int r = blockIdx.x * 4 + (threadIdx.x >> 6);
  int lane = threadIdx.x & 63;
  int c = lane * 2;
  int t = r >> 10, i = r & 1023;
  int n = nnz[r];
  const int* myc = cols + (size_t)r * CAP;
  const float* st = g2s + ((size_t)(t << 10)) * 128;
  float2 acc = *(const float2*)(g2s + (size_t)r * 128 + c);   // self term
  for (int s = 0; s < n; ++s) {
    float2 v = *(const float2*)(st + (size_t)myc[s] * 128 + c);
    acc.x += v.x; acc.y += v.y;
  }
  float dr = dinv[r], m = maskf[r];
  float2 b = *(const float2*)(b2f + c);
  float2 p = *(const float2*)(pe + t * 128 + c);
  float vx = fmaxf(dr * acc.x + b.x, 0.f) * m + p.x;
  float vy = fmaxf(dr * acc.y + b.y, 0.f) * m + p.y;
  size_t o = ((size_t)i * TT + t) * 128 + c;
  splitbf(vx, xh[o], xl[o]);
  splitbf(vy, xh[o + 1], xl[o + 1]);
}

// ---------- split-precision MFMA GEMM v4: pre-split A hi/lo, 64-row tiles, 48 KB LDS, g = blockIdx.y ----------
// (M x 128) @ (128 x 128); B pre-split hi/lo [n][k]. acc = Ah*Bl + Al*Bh + Ah*Bh (bit-identical to v2/v3).
__global__ __launch_bounds__(256) void mfma_gemm(const unsigned short* Ahi, const unsigned short* Alo,
    const unsigned short* Bhi, const unsigned short* Blo,
    const float* scale, const float* bias, float* outf, void* outfin, const int* mode) {
  __shared__ __align__(16) unsigned short Ah[64 * 64];    // 8 KB
  __shared__ __align__(16) unsigned short Al[64 * 64];    // 8 KB
  __shared__ __align__(16) unsigned short Bh[128 * 64];   // 16 KB
  __shared__ __align__(16) unsigned short Bl[128 * 64];   // 16 KB
  int tid = threadIdx.x;
  int rowTile = blockIdx.x * 64;
  int gy = blockIdx.y;
  const unsigned short* Bhp = Bhi + (size_t)gy * 16384;
  const unsigned short* Blp = Blo + (size_t)gy * 16384;
  const float* bp = bias ? (bias + gy * 128) : nullptr;
  float* ofp = outf ? (outf + (size_t)gy * ((size_t)MT * 128)) : nullptr;

  int lane = tid & 63;
  int wid = tid >> 6;
  int wrow = (wid >> 1) * 32, wcol = (wid & 1) * 64;
  f32x4 acc[2][4];
  #pragma unroll
  for (int m = 0; m < 2; ++m)
    #pragma unroll
    for (int n = 0; n < 4; ++n) acc[m][n] = (f32x4){0.f, 0.f, 0.f, 0.f};

  for (int kb = 0; kb < 2; ++kb) {
    __syncthreads();
    // stage A (pure copy of pre-split rows)
    #pragma unroll
    for (int it = 0; it < 2; ++it) {
      int c = it * 256 + tid;
      int r = c >> 3, cc = c & 7;
      int swz = (cc ^ (r & 7)) * 16;
      size_t src = (size_t)(rowTile + r) * 128 + kb * 64 + cc * 8;
      *(uint4*)((char*)Ah + r * 128 + swz) = *(const uint4*)(Ahi + src);
      *(uint4*)((char*)Al + r * 128 + swz) = *(const uint4*)(Alo + src);
    }
    // stage B
    #pragma unroll
    for (int it = 0; it < 4; ++it) {
      int c = it * 256 + tid;
      int r = c >> 3, cc = c & 7;
      int swz = (cc ^ (r & 7)) * 16;
      *(uint4*)((char*)Bh + r * 128 + swz) = *(const uint4*)(Bhp + (size_t)r * 128 + kb * 64 + cc * 8);
      *(uint4*)((char*)Bl + r * 128 + swz) = *(const uint4*)(Blp + (size_t)r * 128 + kb * 64 + cc * 8);
    }
    __syncthreads();
    #pragma unroll
    for (int ks = 0; ks < 2; ++ks) {
      bf16x8 ah[2], al[2], bh[4], bl[4];
      #pragma unroll
      for (int m = 0; m < 2; ++m) {
        int R = wrow + m * 16 + (lane & 15);
        int cc = ks * 4 + (lane >> 4);
        int off = R * 128 + ((cc ^ (R & 7)) * 16);
        ah[m] = *(const bf16x8*)((const char*)Ah + off);
        al[m] = *(const bf16x8*)((const char*)Al + off);
      }
      #pragma unroll
      for (int n = 0; n < 4; ++n) {
        int R = wcol + n * 16 + (lane & 15);
        int cc = ks * 4 + (lane >> 4);
        int off = R * 128 + ((cc ^ (R & 7)) * 16);
        bh[n] = *(const bf16x8*)((const char*)Bh + off);
        bl[n] = *(const bf16x8*)((const char*)Bl + off);
      }
      #pragma unroll
      for (int m = 0; m < 2; ++m)
        #pragma unroll
        for (int n = 0; n < 4; ++n) {
          acc[m][n] = __builtin_amdgcn_mfma_f32_16x16x32_bf16(ah[m], bl[n], acc[m][n], 0, 0, 0);
          acc[m][n] = __builtin_amdgcn_mfma_f32_16x16x32_bf16(al[m], bh[n], acc[m][n], 0, 0, 0);
          acc[m][n] = __builtin_amdgcn_mfma_f32_16x16x32_bf16(ah[m], bh[n], acc[m][n], 0, 0, 0);
        }
    }
  }
  int fp = mode[0];
  #pragma unroll
  for (int m = 0; m < 2; ++m) {
    #pragma unroll
    for (int n = 0; n < 4; ++n) {
      int col = wcol + n * 16 + (lane & 15);
      float bv = bp ? bp[col] : 0.f;
      #pragma unroll
      for (int q = 0; q < 4; ++q) {
        int row = rowTile + wrow + m * 16 + (lane >> 4) * 4 + q;
        float v = acc[m][n][q];
        if (scale) v *= scale[row];
        v += bv;
        size_t o = (size_t)row * 128 + col;
        if (ofp)           ofp[o] = v;
        else if (fp == 0)  ((unsigned short*)outfin)[o] = f2bf(v);
        else               ((float*)outfin)[o] = v;
      }
    }
  }
}

// ---------- attention: thread=(head,t); q,scores,probs in registers; writes o split hi/lo ----------
__global__ __launch_bounds__(256) void attn_kernel(const float* Q, const float* K, const float* V,
                                                   unsigned short* obh, unsigned short* obl) {
  __shared__ __align__(16) float ksm[TT * 128];
  __shared__ __align__(16) float vsm[TT * 128];
  int tid = threadIdx.x;
  size_t base = (size_t)blockIdx.x * (TT * 128);
  for (int i = tid; i < TT * 128 / 4; i += 256) {
    ((float4*)ksm)[i] = ((const float4*)(K + base))[i];
    ((float4*)vsm)[i] = ((const float4*)(V + base))[i];
  }
  int h = tid >> 5, t = tid & 31;
  float q[16];
  if (t < TT) {
    const float4* qp = (const float4*)(Q + base + (size_t)t * 128 + h * 16);
    #pragma unroll
    for (int e = 0; e < 4; ++e) { float4 f = qp[e]; q[4*e] = f.x; q[4*e+1] = f.y; q[4*e+2] = f.z; q[4*e+3] = f.w; }
  }
  __syncthreads();
  if (t >= TT) return;
  float p[TT];
  float mx = -1e30f;
  #pragma unroll
  for (int s = 0; s < TT; ++s) {
    const float4* kp = (const float4*)&ksm[s * 128 + h * 16];
    float d = 0.f;
    #pragma unroll
    for (int e = 0; e < 4; ++e) {
      float4 f = kp[e];
      d += q[4*e] * f.x + q[4*e+1] * f.y + q[4*e+2] * f.z + q[4*e+3] * f.w;
    }
    p[s] = d * 0.25f;  // 1/sqrt(16)
    mx = fmaxf(mx, p[s]);
  }
  float sum = 0.f;
  #pragma unroll
  for (int s = 0; s < TT; ++s) { p[s] = __expf(p[s] - mx); sum += p[s]; }
  float inv = 1.f / sum;
  float o[16];
  #pragma unroll
  for (int e = 0; e < 16; ++e) o[e] = 0.f;
  #pragma unroll
  for (int s = 0; s < TT; ++s) {
    const float4* vp = (const float4*)&vsm[s * 128 + h * 16];
    float ps = p[s] * inv;
    #pragma unroll
    for (int e = 0; e < 4; ++e) {
      float4 f = vp[e];
      o[4*e] += ps * f.x; o[4*e+1] += ps * f.y; o[4*e+2] += ps * f.z; o[4*e+3] += ps * f.w;
    }
  }
  unsigned short hi[16], lo[16];
  #pragma unroll
  for (int e = 0; e < 16; ++e) splitbf(o[e], hi[e], lo[e]);
  size_t oo = base + (size_t)t * 128 + h * 16;
  uint4 ph0, ph1, pl0, pl1;
  ph0.x = hi[0] | ((unsigned)hi[1] << 16);  ph0.y = hi[2] | ((unsigned)hi[3] << 16);
  ph0.z = hi[4] | ((unsigned)hi[5] << 16);  ph0.w = hi[6] | ((unsigned)hi[7] << 16);
  ph1.x = hi[8] | ((unsigned)hi[9] << 16);  ph1.y = hi[10] | ((unsigned)hi[11] << 16);
  ph1.z = hi[12] | ((unsigned)hi[13] << 16); ph1.w = hi[14] | ((unsigned)hi[15] << 16);
  pl0.x = lo[0] | ((unsigned)lo[1] << 16);  pl0.y = lo[2] | ((unsigned)lo[3] << 16);
  pl0.z = lo[4] | ((unsigned)lo[5] << 16);  pl0.w = lo[6] | ((unsigned)lo[7] << 16);
  pl1.x = lo[8] | ((unsigned)lo[9] << 16);  pl1.y = lo[10] | ((unsigned)lo[11] << 16);
  pl1.z = lo[12] | ((unsigned)lo[13] << 16); pl1.w = lo[14] | ((unsigned)lo[15] << 16);
  *(uint4*)(obh + oo) = ph0; *(uint4*)(obh + oo + 8) = ph1;
  *(uint4*)(obl + oo) = pl0; *(uint4*)(obl + oo + 8) = pl1;
}

// ---------- launch ----------
extern "C" void kernel_launch(void* const* d_in, const int* in_sizes, int n_in,
                              void* d_out, int out_size, void* d_ws, size_t ws_size,
                              hipStream_t stream) {
  (void)in_sizes; (void)n_in; (void)out_size;
  const void* x_raw = d_in[0];
  const void* adj   = d_in[1];
  const void* ego   = d_in[2];
  const void* W1 = d_in[3];  const void* b1 = d_in[4];
  const void* W2 = d_in[5];  const void* b2 = d_in[6];
  const void* Wq = d_in[7];  const void* bq = d_in[8];
  const void* Wk = d_in[9];  const void* bk = d_in[10];
  const void* Wv = d_in[11]; const void* bv = d_in[12];
  const void* Wqi = d_in[13]; const void* bqi = d_in[14];
  const void* Wki = d_in[15]; const void* bki = d_in[16];
  const void* Wvi = d_in[17]; const void* bvi = d_in[18];
  const void* Wo = d_in[19]; const void* bo = d_in[20];

  char* w = (char*)d_ws;
  auto alloc = [&](size_t b) { char* p = w; w += (b + 255) & ~(size_t)255; return p; };
  int*   mode  = (int*)  alloc(16);
  float* maskf = (float*)alloc((size_t)MT * 4);
  float* dinv  = (float*)alloc((size_t)MT * 4);
  float* pe    = (float*)alloc((size_t)TT * HH * 4);
  float* W1f   = (float*)alloc(384 * 4);
  float* b1f   = (float*)alloc(128 * 4);
  float* b2f   = (float*)alloc(128 * 4);
  float* bof   = (float*)alloc(128 * 4);
  unsigned short* W2h = (unsigned short*)alloc(16384 * 2);
  unsigned short* W2l = (unsigned short*)alloc(16384 * 2);
  unsigned short* Woh = (unsigned short*)alloc(16384 * 2);
  unsigned short* Wol = (unsigned short*)alloc(16384 * 2);
  unsigned short* Wch = (unsigned short*)alloc((size_t)3 * 16384 * 2);
  unsigned short* Wcl = (unsigned short*)alloc((size_t)3 * 16384 * 2);
  float* bqkv  = (float*)alloc(3 * 128 * 4);
  int*   nnz   = (int*)  alloc((size_t)MT * 4);
  int*   cols  = (int*)  alloc((size_t)MT * CAP * 4);
  unsigned short* h1h = (unsigned short*)alloc((size_t)MT * 128 * 2);
  unsigned short* h1l = (unsigned short*)alloc((size_t)MT * 128 * 2);
  unsigned short* xh  = (unsigned short*)alloc((size_t)MT * 128 * 2);
  unsigned short* xl  = (unsigned short*)alloc((size_t)MT * 128 * 2);
  unsigned short* obh = (unsigned short*)alloc((size_t)MT * 128 * 2);
  unsigned short* obl = (unsigned short*)alloc((size_t)MT * 128 * 2);
  float* g2s   = (float*)alloc((size_t)MT * 128 * 4);
  float* qkv   = (float*)alloc((size_t)3 * MT * 128 * 4);
  size_t need = (size_t)(w - (char*)d_ws);
  if (need > ws_size) return;  // diagnostic: absmax will equal max|ref|

  setup_kernel<<<462, 256, 0, stream>>>(x_raw, ego, W1, b1, W2, b2, Wo, bo,
                                        Wq, bq, Wk, bk, Wv, bv, Wqi, bqi, Wki, bki, Wvi, bvi,
                                        mode, pe, W1f, b1f, b2f, bof,
                                        W2h, W2l, Woh, Wol, Wch, Wcl, bqkv, maskf);
  csr_kernel<<<MT / 4, 256, 0, stream>>>(adj, mode, maskf, nnz, cols, dinv);
  spmm1_kernel<<<MT / 4, 256, 0, stream>>>(x_raw, mode, nnz, cols, dinv, W1f, b1f, h1h, h1l);
  mfma_gemm<<<480, 256, 0, stream>>>(h1h, h1l, W2h, W2l, dinv, nullptr, g2s, nullptr, mode);
  spmm2_kernel<<<MT / 4, 256, 0, stream>>>(g2s, nnz, cols, dinv, b2f, maskf, pe, xh, xl);
  mfma_gemm<<<dim3(480, 3), 256, 0, stream>>>(xh, xl, Wch, Wcl, nullptr, bqkv, qkv, nullptr, mode);
  attn_kernel<<<BNN, 256, 0, stream>>>(qkv, qkv + (size_t)MT * 128, qkv + (size_t)2 * MT * 128, obh, obl);
  mfma_gemm<<<480, 256, 0, stream>>>(obh, obl, Woh, Wol, nullptr, bof, nullptr, d_out, mode);
}

// Round 10
// 127.746 us; speedup vs baseline: 1.1924x; 1.0053x over previous
//
#include <hip/hip_runtime.h>
#include <hip/hip_bf16.h>
#include <math.h>

// Problem constants
#define TT  30
#define BNN 1024
#define HH  128
#define MT  (TT*BNN)     // 30720 rows
#define CAP 64           // max nnz per adjacency row (mean ~5.1, 64 is >25 sigma)

typedef short bf16x8 __attribute__((ext_vector_type(8)));
typedef float f32x4 __attribute__((ext_vector_type(4)));

#if defined(__has_builtin)
#if __has_builtin(__builtin_amdgcn_global_load_lds)
#define HAS_GLL 1
#endif
#endif

#ifdef HAS_GLL
typedef const __attribute__((address_space(1))) unsigned int* gas1_t;
typedef __attribute__((address_space(3))) unsigned int* las3_t;
__device__ __forceinline__ void gload16(const void* g, void* l) {
  __builtin_amdgcn_global_load_lds((gas1_t)g, (las3_t)l, 16, 0, 0);
}
#endif

// ---------- helpers ----------
__device__ __forceinline__ float ldf(const void* p, size_t i, int fp) {
  if (fp == 0) { // bf16
    unsigned int w = ((unsigned int)(((const unsigned short*)p)[i])) << 16;
    float f; __builtin_memcpy(&f, &w, 4); return f;
  }
  return ((const float*)p)[i];
}
__device__ __forceinline__ float bf2f(unsigned short u) {
  unsigned int w = ((unsigned int)u) << 16;
  float f; __builtin_memcpy(&f, &w, 4); return f;
}
__device__ __forceinline__ unsigned short f2bf(float f) { // RNE
  unsigned int u; __builtin_memcpy(&u, &f, 4);
  return (unsigned short)((u + 0x7FFFu + ((u >> 16) & 1u)) >> 16);
}
// split f32 into bf16 hi + bf16 lo (residual); hi+lo ~ a with ~2^-17 rel err
__device__ __forceinline__ void splitbf(float a, unsigned short& h, unsigned short& l) {
  h = f2bf(a);
  l = f2bf(a - bf2f(h));
}

// ---------- block-local deterministic dtype detection (same bytes every block -> same result) ----------
__device__ int block_detect_fp(const unsigned short* xw) {   // 0=bf16, 1=f32
  __shared__ int cnt_exp;
  if (threadIdx.x == 0) cnt_exp = 0;
  __syncthreads();
  int local = 0;
  for (int i = threadIdx.x; i < 2048; i += 256) {
    int e = (xw[i] >> 8) & 0x7F;
    if (e >= 0x3A && e <= 0x41) local++;
  }
  atomicAdd(&cnt_exp, local);
  __syncthreads();
  return (cnt_exp > 1536) ? 0 : 1;
}
__device__ int block_detect_ego(const unsigned int* ew) {    // 0=bf16,1=f32,2=bool8,3=int32
  __shared__ int f_odd1, f_any, f_nz;
  if (threadIdx.x == 0) { f_odd1 = 0; f_any = 0; f_nz = 0; }
  __syncthreads();
  int l1 = 0, l2 = 0, l3 = 0;
  for (int i = threadIdx.x; i < 7680; i += 256) {
    unsigned int w = ew[i];
    #pragma unroll
    for (int e = 0; e < 4; ++e) {
      unsigned char b = (w >> (8 * e)) & 0xff;
      if (b == 0x3F) { l2 = 1; if (e == 1) l1 = 1; }
      if (b != 0 && e != 0) l3 = 1;
    }
  }
  if (l1) atomicOr(&f_odd1, 1);
  if (l2) atomicOr(&f_any, 1);
  if (l3) atomicOr(&f_nz, 1);
  __syncthreads();
  return f_odd1 ? 0 : (f_any ? 1 : (f_nz ? 2 : 3));
}

// ---------- fused setup: detect + pe + weight prep + mask expand + combined QKV projections ----------
// bid 0: global mode write; [1,16): pe; [16,147): prep; [147,267): expand_mask; [267,462): combine3
__global__ __launch_bounds__(256) void setup_kernel(
    const void* x_raw, const void* ego,
    const void* W1, const void* b1, const void* W2, const void* b2, const void* Wo, const void* bo,
    const void* Wq, const void* bq, const void* Wk, const void* bk, const void* Wv, const void* bv,
    const void* Wqi, const void* bqi, const void* Wki, const void* bki, const void* Wvi, const void* bvi,
    int* mode, float* pe, float* W1f, float* b1f, float* b2f, float* bof,
    unsigned short* W2h, unsigned short* W2l, unsigned short* Woh, unsigned short* Wol,
    unsigned short* Wch, unsigned short* Wcl, float* bqkv, float* maskf) {
  int bid = blockIdx.x;
  if (bid == 0) {
    int fp = block_detect_fp((const unsigned short*)x_raw);
    int mm = block_detect_ego((const unsigned int*)ego);
    if (threadIdx.x == 0) { mode[0] = fp; mode[1] = mm; }
    return;
  }
  if (bid < 16) {
    // positional embedding (double precision, matches numpy)
    int idx = (bid - 1) * 256 + threadIdx.x;
    int t = idx >> 7, i = idx & 127, j = i >> 1;
    double div = exp((double)(2 * j) * (-log(10000.0) / 128.0));
    double ang = (double)t * div;
    pe[idx] = (i & 1) ? (float)cos(ang) : (float)sin(ang);
    return;
  }
  if (bid < 147) {
    int fp = block_detect_fp((const unsigned short*)x_raw);
    int idx = (bid - 16) * 256 + threadIdx.x;
    if (idx < 16384) { int k = idx >> 7, h = idx & 127; splitbf(ldf(W2, idx, fp), W2h[h * 128 + k], W2l[h * 128 + k]); return; }
    idx -= 16384;
    if (idx < 16384) { int k = idx >> 7, h = idx & 127; splitbf(ldf(Wo, idx, fp), Woh[h * 128 + k], Wol[h * 128 + k]); return; }
    idx -= 16384;
    if (idx < 384) { W1f[idx] = ldf(W1, idx, fp); return; } idx -= 384;
    if (idx < 128) { b1f[idx] = ldf(b1, idx, fp); return; } idx -= 128;
    if (idx < 128) { b2f[idx] = ldf(b2, idx, fp); return; } idx -= 128;
    if (idx < 128) { bof[idx] = ldf(bo, idx, fp); return; }
    return;
  }
  if (bid < 267) {
    // ego mask (B,T,N) -> (T,BN) as f32 0/1
    int mm = block_detect_ego((const unsigned int*)ego);
    int idx = (bid - 147) * 256 + threadIdx.x;
    int t = idx >> 10, p = idx & 1023, b = p >> 8, n = p & 255;
    size_t e = (size_t)b * (TT * 256) + (size_t)t * 256 + n;
    bool nz;
    if      (mm == 0) nz = ((const unsigned short*)ego)[e] != 0;
    else if (mm == 1) nz = ((const float*)ego)[e] != 0.f;
    else if (mm == 2) nz = ((const unsigned char*)ego)[e] != 0;
    else              nz = ((const int*)ego)[e] != 0;
    maskf[idx] = nz ? 1.f : 0.f;
    return;
  }
  // combine3: (Wa@Wb)^T split hi/lo bf16; bc = ba@Wb + bb (f32)
  int fp = block_detect_fp((const unsigned short*)x_raw);
  int cb = bid - 267;
  int g = cb / 65;
  const void* Wa = (g == 0) ? Wq : (g == 1) ? Wk : Wv;
  const void* ba = (g == 0) ? bq : (g == 1) ? bk : bv;
  const void* Wb = (g == 0) ? Wqi : (g == 1) ? Wki : Wvi;
  const void* bb = (g == 0) ? bqi : (g == 1) ? bki : bvi;
  unsigned short* Wh = Wch + (size_t)g * 16384;
  unsigned short* Wl = Wcl + (size_t)g * 16384;
  float* bc = bqkv + g * 128;
  int idx = (cb % 65) * 256 + threadIdx.x;
  if (idx < 16384) {
    int k = idx >> 7, h = idx & 127;
    float s = 0.f;
    #pragma unroll 8
    for (int m = 0; m < 128; ++m) s += ldf(Wa, k * 128 + m, fp) * ldf(Wb, m * 128 + h, fp);
    splitbf(s, Wh[h * 128 + k], Wl[h * 128 + k]);
  } else if (idx < 16512) {
    int h = idx - 16384;
    float s = ldf(bb, h, fp);
    #pragma unroll 8
    for (int m = 0; m < 128; ++m) s += ldf(ba, m, fp) * ldf(Wb, m * 128 + h, fp);
    bc[h] = s;
  }
}

// ---------- CSR build + degree/dinv (deterministic, ballot-ordered, vectorized loads) ----------
__global__ __launch_bounds__(256) void csr_kernel(const void* A, const int* mode, const float* maskf,
                                                  int* nnz, int* cols, float* dinv) {
  int fp = mode[0];
  int r = blockIdx.x * 4 + (threadIdx.x >> 6);
  int lane = threadIdx.x & 63;
  int t = r >> 10, i = r & 1023;
  int tb = t << 10;
  if (maskf[r] == 0.f) { if (lane == 0) { nnz[r] = 0; dinv[r] = 0.f; } return; }
  int* myc = cols + (size_t)r * CAP;
  int cnt = 0;
  unsigned long long lmask = (1ull << lane) - 1ull;
  if (fp == 1) {
    const float* Ar = (const float*)A + (size_t)t * BNN * BNN + (size_t)i * BNN;
    #pragma unroll
    for (int it = 0; it < 4; ++it) {
      int j0 = it * 256 + lane * 4;
      float4 av = *(const float4*)(Ar + j0);
      float4 mv = *(const float4*)(maskf + tb + j0);
      float va[4] = {av.x * mv.x, av.y * mv.y, av.z * mv.z, av.w * mv.w};
      #pragma unroll
      for (int e = 0; e < 4; ++e) {
        bool hit = va[e] != 0.f;
        unsigned long long bal = __ballot(hit);
        if (hit) { int pos = cnt + __popcll(bal & lmask); if (pos < CAP) myc[pos] = j0 + e; }
        cnt += __popcll(bal);
      }
    }
  } else {
    const unsigned short* Ar = (const unsigned short*)A + (size_t)t * BNN * BNN + (size_t)i * BNN;
    #pragma unroll
    for (int it = 0; it < 2; ++it) {
      int j0 = it * 512 + lane * 8;
      uint4 av = *(const uint4*)(Ar + j0);
      unsigned int wv[4] = {av.x, av.y, av.z, av.w};
      float4 m0 = *(const float4*)(maskf + tb + j0);
      float4 m1 = *(const float4*)(maskf + tb + j0 + 4);
      float mm[8] = {m0.x, m0.y, m0.z, m0.w, m1.x, m1.y, m1.z, m1.w};
      #pragma unroll
      for (int e = 0; e < 8; ++e) {
        unsigned short u = (wv[e >> 1] >> ((e & 1) * 16)) & 0xffff;
        bool hit = (u != 0) && (mm[e] != 0.f);
        unsigned long long bal = __ballot(hit);
        if (hit) { int pos = cnt + __popcll(bal & lmask); if (pos < CAP) myc[pos] = j0 + e; }
        cnt += __popcll(bal);
      }
    }
  }
  if (lane == 0) { nnz[r] = cnt > CAP ? CAP : cnt; dinv[r] = rsqrtf((float)cnt + 1.0f); }
}

// ---------- GCN layer 1: h1 = relu(dinv_r*(S @ W1) + b1), S = sum_j dinv_j x_j; writes hi/lo bf16 ----------
__global__ __launch_bounds__(256) void spmm1_kernel(const void* x, const int* mode, const int* nnz,
    const int* cols, const float* dinv, const float* W1f, const float* b1f,
    unsigned short* h1h, unsigned short* h1l) {
  int fp = mode[0];
  int r = blockIdx.x * 4 + (threadIdx.x >> 6);
  int lane = threadIdx.x & 63;
  int tbase = (r >> 10) << 10;  // t * 1024
  int n = nnz[r];
  float s0 = 0.f, s1 = 0.f, s2 = 0.f;
  int j = -1;
  if (lane < n) j = tbase + cols[(size_t)r * CAP + lane];   // GLOBAL row id
  else if (lane == n) j = r;  // self-loop term; n<64 guaranteed
  if (j >= 0) {
    float dj = dinv[j];
    s0 = dj * ldf(x, (size_t)j * 3 + 0, fp);
    s1 = dj * ldf(x, (size_t)j * 3 + 1, fp);
    s2 = dj * ldf(x, (size_t)j * 3 + 2, fp);
  }
  #pragma unroll
  for (int d = 1; d < 64; d <<= 1) {
    s0 += __shfl_xor(s0, d);
    s1 += __shfl_xor(s1, d);
    s2 += __shfl_xor(s2, d);
  }
  float dr = dinv[r];
  #pragma unroll
  for (int u = 0; u < 2; ++u) {
    int h = lane + u * 64;
    float v = dr * (s0 * W1f[h] + s1 * W1f[128 + h] + s2 * W1f[256 + h]) + b1f[h];
    splitbf(fmaxf(v, 0.f), h1h[(size_t)r * 128 + h], h1l[(size_t)r * 128 + h]);
  }
}

// ---------- GCN layer 2 sparse aggregate + epilogue -> x_seq hi/lo bf16 (wave per row, float2/lane) ----------
__global__ __launch_bounds__(256) void spmm2_kernel(const float* g2s, const int* nnz, const int* cols,
    const float* dinv, const float* b2f, const float* maskf, const float* pe,
    unsigned short* xh, unsigned short* xl) {
  int r = blockIdx.x * 4 + (threadIdx.x >> 6);
  int lane = threadIdx.x & 63;
  int c = lane * 2;
  int t = r >> 10, i = r & 1023;
  int n = nnz[r];
  const int* myc = cols + (size_t)r * CAP;
  const float* st = g2s + ((size_t)(t << 10)) * 128;
  float2 acc = *(const float2*)(g2s + (size_t)r * 128 + c);   // self term
  for (int s = 0; s < n; ++s) {
    float2 v = *(const float2*)(st + (size_t)myc[s] * 128 + c);
    acc.x += v.x; acc.y += v.y;
  }
  float dr = dinv[r], m = maskf[r];
  float2 b = *(const float2*)(b2f + c);
  float2 p = *(const float2*)(pe + t * 128 + c);
  float vx = fmaxf(dr * acc.x + b.x, 0.f) * m + p.x;
  float vy = fmaxf(dr * acc.y + b.y, 0.f) * m + p.y;
  size_t o = ((size_t)i * TT + t) * 128 + c;
  splitbf(vx, xh[o], xl[o]);
  splitbf(vy, xh[o + 1], xl[o + 1]);
}

// ---------- split-precision MFMA GEMM v5: global_load_lds staging (pre-swizzled source, linear LDS dest) ----------
// (M x 128) @ (128 x 128); A,B pre-split hi/lo bf16; B [n][k]. acc = Ah*Bl + Al*Bh + Ah*Bh (bit-identical to v4).
// LDS layout identical to v4: row r, 16B slot s holds source chunk cc = s ^ (r&7).
// Since 1KB-chunks are 8-row aligned, r&7 == lane>>3, so source chunk = (lane&7) ^ (lane>>3).
__global__ __launch_bounds__(256) void mfma_gemm(const unsigned short* Ahi, const unsigned short* Alo,
    const unsigned short* Bhi, const unsigned short* Blo,
    const float* scale, const float* bias, float* outf, void* outfin, const int* mode) {
  __shared__ __align__(16) unsigned short Ah[64 * 64];    // 8 KB
  __shared__ __align__(16) unsigned short Al[64 * 64];    // 8 KB
  __shared__ __align__(16) unsigned short Bh[128 * 64];   // 16 KB
  __shared__ __align__(16) unsigned short Bl[128 * 64];   // 16 KB
  int tid = threadIdx.x;
  int rowTile = blockIdx.x * 64;
  int gy = blockIdx.y;
  const unsigned short* Bhp = Bhi + (size_t)gy * 16384;
  const unsigned short* Blp = Blo + (size_t)gy * 16384;
  const float* bp = bias ? (bias + gy * 128) : nullptr;
  float* ofp = outf ? (outf + (size_t)gy * ((size_t)MT * 128)) : nullptr;

  int lane = tid & 63;
  int wid = tid >> 6;
  int wrow = (wid >> 1) * 32, wcol = (wid & 1) * 64;
  f32x4 acc[2][4];
  #pragma unroll
  for (int m = 0; m < 2; ++m)
    #pragma unroll
    for (int n = 0; n < 4; ++n) acc[m][n] = (f32x4){0.f, 0.f, 0.f, 0.f};

  for (int kb = 0; kb < 2; ++kb) {
    __syncthreads();
#ifdef HAS_GLL
    {
      int lrow = lane >> 3;                 // row within 8-row chunk
      int cc = (lane & 7) ^ lrow;           // pre-swizzled source chunk
      int soff = kb * 128 + cc * 16;        // byte offset within a 256B source row
      // A: 8 chunks (64 rows), 2 per wave
      #pragma unroll
      for (int i = 0; i < 2; ++i) {
        int c = wid * 2 + i;
        size_t gb = (size_t)(rowTile + c * 8 + lrow) * 256 + soff;
        gload16((const char*)Ahi + gb, (char*)Ah + c * 1024);
        gload16((const char*)Alo + gb, (char*)Al + c * 1024);
      }
      // B: 16 chunks (128 rows), 4 per wave
      #pragma unroll
      for (int i = 0; i < 4; ++i) {
        int c = wid * 4 + i;
        size_t gb = (size_t)(c * 8 + lrow) * 256 + soff;
        gload16((const char*)Bhp + gb, (char*)Bh + c * 1024);
        gload16((const char*)Blp + gb, (char*)Bl + c * 1024);
      }
    }
#else
    #pragma unroll
    for (int it = 0; it < 2; ++it) {
      int c = it * 256 + tid;
      int r = c >> 3, cc = c & 7;
      int swz = (cc ^ (r & 7)) * 16;
      size_t src = (size_t)(rowTile + r) * 128 + kb * 64 + cc * 8;
      *(uint4*)((char*)Ah + r * 128 + swz) = *(const uint4*)(Ahi + src);
      *(uint4*)((char*)Al + r * 128 + swz) = *(const uint4*)(Alo + src);
    }
    #pragma unroll
    for (int it = 0; it < 4; ++it) {
      int c = it * 256 + tid;
      int r = c >> 3, cc = c & 7;
      int swz = (cc ^ (r & 7)) * 16;
      *(uint4*)((char*)Bh + r * 128 + swz) = *(const uint4*)(Bhp + (size_t)r * 128 + kb * 64 + cc * 8);
      *(uint4*)((char*)Bl + r * 128 + swz) = *(const uint4*)(Blp + (size_t)r * 128 + kb * 64 + cc * 8);
    }
#endif
    __syncthreads();
    #pragma unroll
    for (int ks = 0; ks < 2; ++ks) {
      bf16x8 ah[2], al[2], bh[4], bl[4];
      #pragma unroll
      for (int m = 0; m < 2; ++m) {
        int R = wrow + m * 16 + (lane & 15);
        int cc = ks * 4 + (lane >> 4);
        int off = R * 128 + ((cc ^ (R & 7)) * 16);
        ah[m] = *(const bf16x8*)((const char*)Ah + off);
        al[m] = *(const bf16x8*)((const char*)Al + off);
      }
      #pragma unroll
      for (int n = 0; n < 4; ++n) {
        int R = wcol + n * 16 + (lane & 15);
        int cc = ks * 4 + (lane >> 4);
        int off = R * 128 + ((cc ^ (R & 7)) * 16);
        bh[n] = *(const bf16x8*)((const char*)Bh + off);
        bl[n] = *(const bf16x8*)((const char*)Bl + off);
      }
      #pragma unroll
      for (int m = 0; m < 2; ++m)
        #pragma unroll
        for (int n = 0; n < 4; ++n) {
          acc[m][n] = __builtin_amdgcn_mfma_f32_16x16x32_bf16(ah[m], bl[n], acc[m][n], 0, 0, 0);
          acc[m][n] = __builtin_amdgcn_mfma_f32_16x16x32_bf16(al[m], bh[n], acc[m][n], 0, 0, 0);
          acc[m][n] = __builtin_amdgcn_mfma_f32_16x16x32_bf16(ah[m], bh[n], acc[m][n], 0, 0, 0);
        }
    }
  }
  int fp = mode[0];
  #pragma unroll
  for (int m = 0; m < 2; ++m) {
    #pragma unroll
    for (int n = 0; n < 4; ++n) {
      int col = wcol + n * 16 + (lane & 15);
      float bv = bp ? bp[col] : 0.f;
      #pragma unroll
      for (int q = 0; q < 4; ++q) {
        int row = rowTile + wrow + m * 16 + (lane >> 4) * 4 + q;
        float v = acc[m][n][q];
        if (scale) v *= scale[row];
        v += bv;
        size_t o = (size_t)row * 128 + col;
        if (ofp)           ofp[o] = v;
        else if (fp == 0)  ((unsigned short*)outfin)[o] = f2bf(v);
        else               ((float*)outfin)[o] = v;
      }
    }
  }
}

// ---------- attention: thread=(head,t); q,scores,probs in registers; writes o split hi/lo ----------
__global__ __launch_bounds__(256) void attn_kernel(const float* Q, const float* K, const float* V,
                                                   unsigned short* obh, unsigned short* obl) {
  __shared__ __align__(16) float ksm[TT * 128];
  __shared__ __align__(16) float vsm[TT * 128];
  int tid = threadIdx.x;
  size_t base = (size_t)blockIdx.x * (TT * 128);
  for (int i = tid; i < TT * 128 / 4; i += 256) {
    ((float4*)ksm)[i] = ((const float4*)(K + base))[i];
    ((float4*)vsm)[i] = ((const float4*)(V + base))[i];
  }
  int h = tid >> 5, t = tid & 31;
  float q[16];
  if (t < TT) {
    const float4* qp = (const float4*)(Q + base + (size_t)t * 128 + h * 16);
    #pragma unroll
    for (int e = 0; e < 4; ++e) { float4 f = qp[e]; q[4*e] = f.x; q[4*e+1] = f.y; q[4*e+2] = f.z; q[4*e+3] = f.w; }
  }
  __syncthreads();
  if (t >= TT) return;
  float p[TT];
  float mx = -1e30f;
  #pragma unroll
  for (int s = 0; s < TT; ++s) {
    const float4* kp = (const float4*)&ksm[s * 128 + h * 16];
    float d = 0.f;
    #pragma unroll
    for (int e = 0; e < 4; ++e) {
      float4 f = kp[e];
      d += q[4*e] * f.x + q[4*e+1] * f.y + q[4*e+2] * f.z + q[4*e+3] * f.w;
    }
    p[s] = d * 0.25f;  // 1/sqrt(16)
    mx = fmaxf(mx, p[s]);
  }
  float sum = 0.f;
  #pragma unroll
  for (int s = 0; s < TT; ++s) { p[s] = __expf(p[s] - mx); sum += p[s]; }
  float inv = 1.f / sum;
  float o[16];
  #pragma unroll
  for (int e = 0; e < 16; ++e) o[e] = 0.f;
  #pragma unroll
  for (int s = 0; s < TT; ++s) {
    const float4* vp = (const float4*)&vsm[s * 128 + h * 16];
    float ps = p[s] * inv;
    #pragma unroll
    for (int e = 0; e < 4; ++e) {
      float4 f = vp[e];
      o[4*e] += ps * f.x; o[4*e+1] += ps * f.y; o[4*e+2] += ps * f.z; o[4*e+3] += ps * f.w;
    }
  }
  unsigned short hi[16], lo[16];
  #pragma unroll
  for (int e = 0; e < 16; ++e) splitbf(o[e], hi[e], lo[e]);
  size_t oo = base + (size_t)t * 128 + h * 16;
  uint4 ph0, ph1, pl0, pl1;
  ph0.x = hi[0] | ((unsigned)hi[1] << 16);  ph0.y = hi[2] | ((unsigned)hi[3] << 16);
  ph0.z = hi[4] | ((unsigned)hi[5] << 16);  ph0.w = hi[6] | ((unsigned)hi[7] << 16);
  ph1.x = hi[8] | ((unsigned)hi[9] << 16);  ph1.y = hi[10] | ((unsigned)hi[11] << 16);
  ph1.z = hi[12] | ((unsigned)hi[13] << 16); ph1.w = hi[14] | ((unsigned)hi[15] << 16);
  pl0.x = lo[0] | ((unsigned)lo[1] << 16);  pl0.y = lo[2] | ((unsigned)lo[3] << 16);
  pl0.z = lo[4] | ((unsigned)lo[5] << 16);  pl0.w = lo[6] | ((unsigned)lo[7] << 16);
  pl1.x = lo[8] | ((unsigned)lo[9] << 16);  pl1.y = lo[10] | ((unsigned)lo[11] << 16);
  pl1.z = lo[12] | ((unsigned)lo[13] << 16); pl1.w = lo[14] | ((unsigned)lo[15] << 16);
  *(uint4*)(obh + oo) = ph0; *(uint4*)(obh + oo + 8) = ph1;
  *(uint4*)(obl + oo) = pl0; *(uint4*)(obl + oo + 8) = pl1;
}

// ---------- launch ----------
extern "C" void kernel_launch(void* const* d_in, const int* in_sizes, int n_in,
                              void* d_out, int out_size, void* d_ws, size_t ws_size,
                              hipStream_t stream) {
  (void)in_sizes; (void)n_in; (void)out_size;
  const void* x_raw = d_in[0];
  const void* adj   = d_in[1];
  const void* ego   = d_in[2];
  const void* W1 = d_in[3];  const void* b1 = d_in[4];
  const void* W2 = d_in[5];  const void* b2 = d_in[6];
  const void* Wq = d_in[7];  const void* bq = d_in[8];
  const void* Wk = d_in[9];  const void* bk = d_in[10];
  const void* Wv = d_in[11]; const void* bv = d_in[12];
  const void* Wqi = d_in[13]; const void* bqi = d_in[14];
  const void* Wki = d_in[15]; const void* bki = d_in[16];
  const void* Wvi = d_in[17]; const void* bvi = d_in[18];
  const void* Wo = d_in[19]; const void* bo = d_in[20];

  char* w = (char*)d_ws;
  auto alloc = [&](size_t b) { char* p = w; w += (b + 255) & ~(size_t)255; return p; };
  int*   mode  = (int*)  alloc(16);
  float* maskf = (float*)alloc((size_t)MT * 4);
  float* dinv  = (float*)alloc((size_t)MT * 4);
  float* pe    = (float*)alloc((size_t)TT * HH * 4);
  float* W1f   = (float*)alloc(384 * 4);
  float* b1f   = (float*)alloc(128 * 4);
  float* b2f   = (float*)alloc(128 * 4);
  float* bof   = (float*)alloc(128 * 4);
  unsigned short* W2h = (unsigned short*)alloc(16384 * 2);
  unsigned short* W2l = (unsigned short*)alloc(16384 * 2);
  unsigned short* Woh = (unsigned short*)alloc(16384 * 2);
  unsigned short* Wol = (unsigned short*)alloc(16384 * 2);
  unsigned short* Wch = (unsigned short*)alloc((size_t)3 * 16384 * 2);
  unsigned short* Wcl = (unsigned short*)alloc((size_t)3 * 16384 * 2);
  float* bqkv  = (float*)alloc(3 * 128 * 4);
  int*   nnz   = (int*)  alloc((size_t)MT * 4);
  int*   cols  = (int*)  alloc((size_t)MT * CAP * 4);
  unsigned short* h1h = (unsigned short*)alloc((size_t)MT * 128 * 2);
  unsigned short* h1l = (unsigned short*)alloc((size_t)MT * 128 * 2);
  unsigned short* xh  = (unsigned short*)alloc((size_t)MT * 128 * 2);
  unsigned short* xl  = (unsigned short*)alloc((size_t)MT * 128 * 2);
  unsigned short* obh = (unsigned short*)alloc((size_t)MT * 128 * 2);
  unsigned short* obl = (unsigned short*)alloc((size_t)MT * 128 * 2);
  float* g2s   = (float*)alloc((size_t)MT * 128 * 4);
  float* qkv   = (float*)alloc((size_t)3 * MT * 128 * 4);
  size_t need = (size_t)(w - (char*)d_ws);
  if (need > ws_size) return;  // diagnostic: absmax will equal max|ref|

  setup_kernel<<<462, 256, 0, stream>>>(x_raw, ego, W1, b1, W2, b2, Wo, bo,
                                        Wq, bq, Wk, bk, Wv, bv, Wqi, bqi, Wki, bki, Wvi, bvi,
                                        mode, pe, W1f, b1f, b2f, bof,
                                        W2h, W2l, Woh, Wol, Wch, Wcl, bqkv, maskf);
  csr_kernel<<<MT / 4, 256, 0, stream>>>(adj, mode, maskf, nnz, cols, dinv);
  spmm1_kernel<<<MT / 4, 256, 0, stream>>>(x_raw, mode, nnz, cols, dinv, W1f, b1f, h1h, h1l);
  mfma_gemm<<<480, 256, 0, stream>>>(h1h, h1l, W2h, W2l, dinv, nullptr, g2s, nullptr, mode);
  spmm2_kernel<<<MT / 4, 256, 0, stream>>>(g2s, nnz, cols, dinv, b2f, maskf, pe, xh, xl);
  mfma_gemm<<<dim3(480, 3), 256, 0, stream>>>(xh, xl, Wch, Wcl, nullptr, bqkv, qkv, nullptr, mode);
  attn_kernel<<<BNN, 256, 0, stream>>>(qkv, qkv + (size_t)MT * 128, qkv + (size_t)2 * MT * 128, obh, obl);
  mfma_gemm<<<480, 256, 0, stream>>>(obh, obl, Woh, Wol, nullptr, bof, nullptr, d_out, mode);
}